// Round 9
// baseline (414.237 us; speedup 1.0000x reference)
//
#include <hip/hip_runtime.h>
#include <hip/hip_bf16.h>
#include <cstdint>

// Problem constants
#define BATCH 2048
#define MF    40                 // num fields
#define DDIM  64                 // embedding dim
#define LDIM  128                // hidden size per CIN layer
#define ROWS  (BATCH * DDIM)     // 131072 (b,d) rows

typedef __attribute__((ext_vector_type(4)))  short    short4_t;
typedef __attribute__((ext_vector_type(8)))  short    short8;
typedef __attribute__((ext_vector_type(8)))  __bf16   bf16x8;
typedef __attribute__((ext_vector_type(2)))  float    floatx2;
typedef __attribute__((ext_vector_type(4)))  float    floatx4;
typedef __attribute__((ext_vector_type(16))) float    floatx16;

// POST-MORTEM LEDGER (do not revisit):
//  R1: t-split 4-blocks/CU REGRESSED (2x LDS traffic, 4x barriers, spill).
//  R2: NT hints REGRESSED (scattered NT dwords -> partial-line writes).
//  R3: anti-phase stagger NEUTRAL; zero-C MFMA init NEUTRAL.
//  R4: ring-3 + cap<256 CATASTROPHIC (runtime slot bases -> spill). Ring
//      addressing must be compile-time; launch-bounds cap must stay 256.
//  R5: __builtin_nontemporal_load needs clang ext_vector types.
//  R6: coalesced wprep; ~55us bench-minus-k_cin gap = fixed harness overhead.
//  R7: 2-unit phases NEUTRAL -> barrier COUNT irrelevant; serial section
//      scales with phase, duty cycle invariant.
//  R8: MERGED BLOCK (512 thr, 4 batches, one shared W-ring) WIN 393->370.
//      Shared staging halves per-CU stage traffic. VGPR 120, no spill.
//  Model (R8 corrected): 32x32x16 MFMA = ~32 cyc on its SIMD pipe; per wave
//      per unit 512 cyc demand in T~4440 -> duty ~46-55% with lockstep waves.
//      Idle = lockstep serial phase (unit-top + epilogue + converge).
//  R9 (this round): (a) L0 kk==3 MFMA skip (W0t kk=3 is all zeros; -5%
//      matrix work, staging/gates byte-identical, absmax must stay exact);
//      (b) m-loop unroll 2 -> scheduler may overlap m's epilogue with m+1's
//      MFMA issue under the 256-reg cap. Tripwire: VGPR>200 / WRITE>10MB.

__device__ __forceinline__ unsigned short f32_to_bf16(float f) {
    union { float f; uint32_t u; } v; v.f = f;
    uint32_t u = v.u;
    uint32_t r = (u + 0x7fffu + ((u >> 16) & 1u)) >> 16;   // RNE
    return (unsigned short)r;
}

// raw barrier: execution sync WITHOUT __syncthreads' vmcnt(0)/lgkmcnt(0) drain
__device__ __forceinline__ void barrier_raw() {
    asm volatile("s_barrier" ::: "memory");
}
__device__ __forceinline__ void lgkmwait0() {
    asm volatile("s_waitcnt lgkmcnt(0)" ::: "memory");
}
template <int N> __device__ __forceinline__ void vmwait() {
    if constexpr (N == 0)  asm volatile("s_waitcnt vmcnt(0)"  ::: "memory");
    if constexpr (N == 2)  asm volatile("s_waitcnt vmcnt(2)"  ::: "memory");
    if constexpr (N == 4)  asm volatile("s_waitcnt vmcnt(4)"  ::: "memory");
    if constexpr (N == 6)  asm volatile("s_waitcnt vmcnt(6)"  ::: "memory");
}

// ---------------------------------------------------------------------------
// W prep, coalesced (R6, working). One block per (layer, m, kk) 16h x 128l
// tile: 800 x 256. floatx4 NT load -> bf16 LDS tile -> short8 store.
//   Wt[m][kk][cb][lane][j] = W[m][ kk*16 + (lane>>5)*8 + j ][ cb*32 + (lane&31) ]
// W0 padded to KK=4 (h in [40,64) -> 0).
// ---------------------------------------------------------------------------
__global__ __launch_bounds__(256) void k_wprep_all(
    const float* __restrict__ W0, const float* __restrict__ W1,
    const float* __restrict__ W2,
    unsigned short* __restrict__ W0t,
    unsigned short* __restrict__ W1t,
    unsigned short* __restrict__ W2t) {
    __shared__ unsigned short t16[16 * 128];   // bf16 tile [h_local][l]

    int bi = blockIdx.x;                 // W0: 160 tiles, W1/W2: 320 each
    const float* W; unsigned short* Wt; int KK, H;
    if (bi < 160)      { W = W0; Wt = W0t; KK = 4; H = 40; }
    else if (bi < 480) { bi -= 160; W = W1; Wt = W1t; KK = 8; H = 128; }
    else               { bi -= 480; W = W2; Wt = W2t; KK = 8; H = 128; }
    const int tid = threadIdx.x;
    const int kk = bi % KK, m = bi / KK;

#pragma unroll
    for (int half = 0; half < 2; ++half) {
        const int idx = half * 1024 + tid * 4;      // tile-linear f32 index
        const int hl  = idx >> 7, l = idx & 127;
        const int hg  = kk * 16 + hl;
        floatx4 v = {0.f, 0.f, 0.f, 0.f};
        if (hg < H)
            v = __builtin_nontemporal_load(
                (const floatx4*)&W[((size_t)m * H + hg) * LDIM + l]);
        unsigned short o[4];
        o[0] = f32_to_bf16(v.x); o[1] = f32_to_bf16(v.y);
        o[2] = f32_to_bf16(v.z); o[3] = f32_to_bf16(v.w);
        *(short4_t*)&t16[idx] = *(const short4_t*)o;
    }
    __syncthreads();

    const int lane = tid & 63, cb = tid >> 6;
    const int l  = cb * 32 + (lane & 31);
    const int hb = (lane >> 5) * 8;
    unsigned short o[8];
#pragma unroll
    for (int j = 0; j < 8; ++j) o[j] = t16[(hb + j) * 128 + l];
    *(short8*)(Wt + (((size_t)(m * KK + kk) * 4 + cb) * 64 + lane) * 8) =
        *(const short8*)o;
}

// ---------------------------------------------------------------------------
// One layer's K-loop: proven R8 ring-4 / raw-barrier / counted-vmcnt body,
// 512-thread staging. GATE = per-m vmem issues: KK=8: 2+2x2=6; KK=4: 2+2=4.
// R9a: for KK==4 (L0), kk==3's 4 MFMAs are skipped (W0t kk=3 block is all
//      zeros -> contributes exactly +0.0). Staging/prefetch/gates unchanged.
// R9b: m-loop unroll 2 (MF even; per-m gate counts identical both halves;
//      bbuf parity continuous since loop kk-count stays even).
// ---------------------------------------------------------------------------
template <int KK>
__device__ __forceinline__ void layer_loop(
    const unsigned short* __restrict__ Wt,     // bf16 [MF][KK][4][64][8]
    const float* __restrict__ x, int b,
    int lane, int hf, int r31, int cbg0, int cbg1,
    unsigned short* slabf,                     // 4 slots x 8192 shorts
    bf16x8 (&xk)[2][8], floatx16 (&acc)[2][2])
{
    constexpr int UPM  = KK / 4;               // units per m
    constexpr int NU   = MF * UPM;             // total units (16 KB each)
    constexpr int GATE = (KK == 8) ? 6 : 4;    // = vmem insts per m (uniform)

    auto stage = [&](int uu) {                 // stage unit uu (clamped: same bytes)
        int u = uu < NU ? uu : NU - 1;
        const unsigned short* src = Wt + (size_t)u * 8192;
        const int tid = threadIdx.x;
#pragma unroll
        for (int it = 0; it < 2; ++it) {
            int c = it * 512 + tid;
            __builtin_amdgcn_global_load_lds(
                (const __attribute__((address_space(1))) uint32_t*)(src + (size_t)c * 8),
                (__attribute__((address_space(3))) uint32_t*)(&slabf[(size_t)(u & 3) * 8192 + (size_t)c * 8]),
                16, 0, 0);
        }
    };
    auto ldfrag = [&](int u, int frag, int cb) {
        return __builtin_bit_cast(bf16x8, *(const short8*)(
            &slabf[(size_t)(u & 3) * 8192 + ((size_t)(frag * 4 + cb) * 64 + lane) * 8]));
    };

    acc[0][0] = floatx16{}; acc[0][1] = floatx16{};
    acc[1][0] = floatx16{}; acc[1][1] = floatx16{};

    // prologue: fill 3 ring slots; units 0,1 retired before priming
    vmwait<0>();
    stage(0); stage(1); stage(2);
    vmwait<2>();
    barrier_raw();

    bf16x8 bbuf[2][2];                         // W A-frag register ring
#pragma unroll
    for (int p = 0; p < 2; ++p) {
        bbuf[p][0] = ldfrag(0, p, cbg0);
        bbuf[p][1] = ldfrag(0, p, cbg1);
    }

    float s0v = 0.f, s1v = 0.f;

#pragma unroll 2
    for (int m = 0; m < MF; ++m) {
        floatx16 P[2][2] = {};
#pragma unroll
        for (int kk = 0; kk < KK; ++kk) {
            if (kk % 4 == 0) {                 // unit top
                barrier_raw();
                asm volatile("s_setprio 1");
                if (kk == 0) {                 // 2 per-lane scalar scale loads
                    const float* sp = x + ((size_t)b * MF + m) * DDIM + r31;
                    s0v = sp[0];
                    s1v = sp[32];
                }
                stage(m * UPM + kk / 4 + 3);   // 3 units ahead in the ring
            }
            const int slot = kk & 1;
            if (!(KK == 4 && kk == 3)) {       // L0 kk=3 block is all-zero W
                P[0][0] = __builtin_amdgcn_mfma_f32_32x32x16_bf16(bbuf[slot][0], xk[0][kk], P[0][0], 0, 0, 0);
                P[1][0] = __builtin_amdgcn_mfma_f32_32x32x16_bf16(bbuf[slot][0], xk[1][kk], P[1][0], 0, 0, 0);
                P[0][1] = __builtin_amdgcn_mfma_f32_32x32x16_bf16(bbuf[slot][1], xk[0][kk], P[0][1], 0, 0, 0);
                P[1][1] = __builtin_amdgcn_mfma_f32_32x32x16_bf16(bbuf[slot][1], xk[1][kk], P[1][1], 0, 0, 0);
            }
            {   // prefetch 2 kk ahead (crosses unit/m boundary; all compile-time)
                const int j  = kk + 2;
                int mm = m + ((j >= KK) ? 1 : 0);
                if (mm > MF - 1) mm = MF - 1;
                const int jj = (j >= KK) ? (j - KK) : j;
                const int u  = mm * UPM + jj / 4;
                bbuf[slot][0] = ldfrag(u, jj % 4, cbg0);
                bbuf[slot][1] = ldfrag(u, jj % 4, cbg1);
            }
            if (kk % 4 == 3) vmwait<GATE>();   // uniform end-of-unit gate
        }
        asm volatile("s_setprio 0");
        // epilogue: acc += s_t * P (float2 -> v_pk_fma_f32)
#pragma unroll
        for (int t = 0; t < 2; ++t) {
            const float sv = (t == 0) ? s0v : s1v;
            floatx2 s2 = {sv, sv};
#pragma unroll
            for (int cbp = 0; cbp < 2; ++cbp) {
                floatx2*       A = (floatx2*)&acc[t][cbp];
                const floatx2* Q = (const floatx2*)&P[t][cbp];
#pragma unroll
                for (int i = 0; i < 8; ++i) A[i] += s2 * Q[i];
            }
        }
    }
}

// ---------------------------------------------------------------------------
// Fused 3-layer CIN kernel, MERGED BLOCK (R8, proven). Block = 512 thr =
// 8 waves (4 batches x 2 l-halves), ONE shared W-ring; grid 512.
// X intermediates never touch global: layer-boundary exchange overlays all
// four ring slots (4 batches x 16 KB; ring fully drained at boundary).
// NOTE: launch_bounds 2nd arg MUST stay 2 (256-reg cap); smaller caps spill
// this body. Ring addressing must stay compile-time (u&3).
// ---------------------------------------------------------------------------
__global__ __launch_bounds__(512, 2) void k_cin(
    const float* __restrict__ x,               // fp32 [B][MF][DDIM]
    const unsigned short* __restrict__ W0t,    // bf16 [MF][4][4][64][8] (padded)
    const unsigned short* __restrict__ W1t,    // bf16 [MF][8][4][64][8]
    const unsigned short* __restrict__ W2t,    // bf16 [MF][8][4][64][8]
    float* __restrict__ out)                   // fp32 [B][384]
{
    __shared__ unsigned short slab[4][8192];   // 4 x 16 KB W-ring; all 4 slots
                                               // double as the 64 KB X-exchange
    unsigned short* slabf = &slab[0][0];

    const int tid  = threadIdx.x;
    const int lane = tid & 63, wave = tid >> 6;
    const int hf   = lane >> 5, r31 = lane & 31;
    const int rowhalf = wave >> 1, colhalf = wave & 1;   // rowhalf in [0,4)
    const int b = blockIdx.x * 4 + rowhalf;    // this wave's batch
    const int cbg0 = colhalf * 2, cbg1 = colhalf * 2 + 1;

    bf16x8   xk[2][8];                         // B-operand fragments
    floatx16 acc[2][2];                        // [t(row-tile)][cbp], D[l,row]

    // ---- ps: out[b][OFF+l] = sum over all 64 d (butterfly across lanes) ----
    auto write_ps = [&](int OFF) {
#pragma unroll
        for (int cbp = 0; cbp < 2; ++cbp) {
#pragma unroll
            for (int j = 0; j < 16; ++j) {
                float v = acc[0][cbp][j] + acc[1][cbp][j];
                v += __shfl_xor(v, 16);
                v += __shfl_xor(v, 8);
                v += __shfl_xor(v, 4);
                v += __shfl_xor(v, 2);
                v += __shfl_xor(v, 1);
                if (r31 == 0)
                    out[(size_t)b * 384 + OFF + (colhalf * 2 + cbp) * 32 +
                        (j & 3) + 8 * (j >> 2) + 4 * hf] = v;
            }
        }
    };

    // ---- layer boundary: acc -> LDS (reader frag order) -> xk ----
    // Writer element: row = t*32+r31, l = colhalf*64 + cbp*32 + 8g + 4hf + i
    //   => kk = colhalf*4 + cbp*2 + (g>>1), hfr = g&1, j = 4hf+i
    // Xf addr (shorts): rowhalf*8192 + ((t*8+kk)*64 + hfr*32 + r31)*8 + 4hf
    // rowhalf in [0,4): 4 x 16 KB regions = the whole 64 KB slab.
    auto exchange = [&]() {
        vmwait<0>();                           // drain ring staging + ps stores
        barrier_raw();
#pragma unroll
        for (int t = 0; t < 2; ++t)
#pragma unroll
            for (int cbp = 0; cbp < 2; ++cbp)
#pragma unroll
                for (int g = 0; g < 4; ++g) {
                    unsigned short o[4];
#pragma unroll
                    for (int i = 0; i < 4; ++i) o[i] = f32_to_bf16(acc[t][cbp][g * 4 + i]);
                    const int kk  = colhalf * 4 + cbp * 2 + (g >> 1);
                    const int hfr = g & 1;
                    *(short4_t*)(&slabf[(size_t)rowhalf * 8192 +
                        ((size_t)(t * 8 + kk) * 64 + hfr * 32 + r31) * 8 + 4 * hf]) =
                        *(const short4_t*)o;
                }
        lgkmwait0();                           // writes committed to LDS
        barrier_raw();
#pragma unroll
        for (int t = 0; t < 2; ++t)
#pragma unroll
            for (int kk = 0; kk < 8; ++kk)
                xk[t][kk] = __builtin_bit_cast(bf16x8, *(const short8*)(
                    &slabf[(size_t)rowhalf * 8192 + ((size_t)(t * 8 + kk) * 64 + lane) * 8]));
        lgkmwait0();                           // reads in regs before restaging
        barrier_raw();
    };

    // ---- layer 0: xk from original x (KK=4 padded, h<MF else 0) ----
#pragma unroll
    for (int t = 0; t < 2; ++t)
#pragma unroll
        for (int kk = 0; kk < 4; ++kk) {
            unsigned short tmp[8];
#pragma unroll
            for (int j = 0; j < 8; ++j) {
                int h = kk * 16 + hf * 8 + j;
                float v = (h < MF) ? x[((size_t)b * MF + h) * DDIM + t * 32 + r31] : 0.f;
                tmp[j] = f32_to_bf16(v);
            }
            xk[t][kk] = __builtin_bit_cast(bf16x8, *(const short8*)tmp);
        }

    layer_loop<4>(W0t, x, b, lane, hf, r31, cbg0, cbg1, slabf, xk, acc);
    write_ps(0);
    exchange();

    layer_loop<8>(W1t, x, b, lane, hf, r31, cbg0, cbg1, slabf, xk, acc);
    write_ps(128);
    exchange();

    layer_loop<8>(W2t, x, b, lane, hf, r31, cbg0, cbg1, slabf, xk, acc);
    write_ps(256);
}

// ---------------------------------------------------------------------------
extern "C" void kernel_launch(void* const* d_in, const int* in_sizes, int n_in,
                              void* d_out, int out_size, void* d_ws, size_t ws_size,
                              hipStream_t stream) {
    const float* x  = (const float*)d_in[0];
    const float* W0 = (const float*)d_in[1];
    const float* W1 = (const float*)d_in[2];
    const float* W2 = (const float*)d_in[3];
    float* out = (float*)d_out;

    char* ws = (char*)d_ws;
    size_t off = 0;
    auto alloc = [&](size_t bytes) -> void* {
        void* p = ws + off;
        off += (bytes + 255) & ~(size_t)255;
        return p;
    };
    unsigned short* W0t = (unsigned short*)alloc((size_t)MF * 4 * 2048 * 2);   // 0.66 MB
    unsigned short* W1t = (unsigned short*)alloc((size_t)MF * 8 * 2048 * 2);   // 1.31 MB
    unsigned short* W2t = (unsigned short*)alloc((size_t)MF * 8 * 2048 * 2);   // 1.31 MB

    k_wprep_all<<<800, 256, 0, stream>>>(W0, W1, W2, W0t, W1t, W2t);
    k_cin<<<ROWS / 256, 512, 0, stream>>>(x, W0t, W1t, W2t, out);
}